// Round 6
// baseline (116.503 us; speedup 1.0000x reference)
//
#include <hip/hip_runtime.h>
#include <math.h>

// S4 diagonal SSM: B=2, L=2048, H=512, N=64. Chunked: T=64, NC=32.
//   y[cT+t'] = sum_{tau<=t'} K[h,tau]*u[t-tau] + sum_n Sw[b,c,n,h]*Ad^t'
//   Sw = C[n]*Ad*S_c (folded at scan time), K[h,tau] = sum_n C*Bd*Ad^tau (D in K[0]).
// 3 kernels; cooperative grid.sync measured ~70us/sync on gfx950 -- never fuse that way.
// State table packed float4 {Sw, Ad, Ad^16, Ad^32}: 64 dwordx4 loads in k_out
// instead of 192 scalar loads over 3 streams.

#define BATCH   2
#define SEQLEN  2048
#define DMODEL  512
#define DSTATE  64
#define T_CHUNK 64
#define NCHUNK  32
#define RT      16

__device__ __forceinline__ float A_cont(int n) {
    // A[n] = (1 + (n+1)/64)^(-1/2)
    return rsqrtf(1.0f + (float)(n + 1) * (1.0f / 64.0f));
}

// ---------------- Kernel 1: xlocal[b][c][n][h] (16 states/thread) ----------------
__global__ __launch_bounds__(256) void k_xlocal(const float* __restrict__ u,
                                                const float* __restrict__ B_re,
                                                const float* __restrict__ log_dt,
                                                float* __restrict__ xl) {
    int tid = blockIdx.x * 256 + threadIdx.x;      // 131072 threads
    int h  = tid & (DMODEL - 1);
    int ng = (tid >> 9) & 3;                       // 16 n per group
    int c  = (tid >> 11) & (NCHUNK - 1);
    int b  = tid >> 16;
    float delta = expf(log_dt[h]);
    float Ad[16], Bd[16], x[16];
    #pragma unroll
    for (int nn = 0; nn < 16; ++nn) {
        int n = ng * 16 + nn;
        float dA = delta * A_cont(n);
        Ad[nn] = expf(dA);
        Bd[nn] = expm1f(dA) * B_re[n] * delta;
        x[nn] = 0.0f;
    }
    const float* up = u + ((size_t)(b * SEQLEN + c * T_CHUNK)) * DMODEL + h;
    #pragma unroll 4
    for (int s = 0; s < T_CHUNK; ++s) {
        float uv = up[(size_t)s * DMODEL];         // coalesced in h
        #pragma unroll
        for (int nn = 0; nn < 16; ++nn)
            x[nn] = fmaf(Ad[nn], x[nn], Bd[nn] * uv);
    }
    float* xp = xl + ((size_t)((b * NCHUNK + c) * DSTATE + ng * 16)) * DMODEL + h;
    #pragma unroll
    for (int nn = 0; nn < 16; ++nn) xp[(size_t)nn * DMODEL] = x[nn];
}

// ---------------- Kernel 2: chunk scan -> packed state table + Kbuf setup ----------------
// Reads raw xl; scan chain on raw S; stores SwT[b][c-1][n][h] = {C*Ad*S_c, Ad, Ad^16, Ad^32}.
// tid<32768 additionally computes Kbuf[j][h] (D folded at j=0).
__global__ __launch_bounds__(256) void k_scanset(const float* __restrict__ B_re,
                                                 const float* __restrict__ C_re,
                                                 const float* __restrict__ log_dt,
                                                 const float* __restrict__ Dp,
                                                 const float* __restrict__ xl,
                                                 float4* __restrict__ SwT,
                                                 float* __restrict__ Kbuf) {
    int tid = blockIdx.x * 256 + threadIdx.x;      // 65536 threads
    int h = tid & (DMODEL - 1);
    int n = (tid >> 9) & (DSTATE - 1);
    int b = tid >> 15;
    float delta = expf(log_dt[h]);
    float Ad = expf(delta * A_cont(n));
    float Ad2  = Ad * Ad;
    float Ad4  = Ad2 * Ad2;
    float Ad8  = Ad4 * Ad4;
    float Ad16 = Ad8 * Ad8;
    float Ad32 = Ad16 * Ad16;
    float ApT  = Ad32 * Ad32;                      // Ad^64 = Ad^T
    float CAd  = C_re[n] * Ad;

    const float* base = xl + ((size_t)(b * NCHUNK * DSTATE + n)) * DMODEL + h;
    float v[NCHUNK - 1];
    #pragma unroll
    for (int c = 0; c < NCHUNK - 1; ++c)
        v[c] = base[(size_t)c * DSTATE * DMODEL];  // 31 independent loads
    float s = 0.0f;
    float4* sw = SwT + ((size_t)(b * (NCHUNK - 1) * DSTATE + n)) * DMODEL + h;
    #pragma unroll
    for (int c = 0; c < NCHUNK - 1; ++c) {
        s = fmaf(ApT, s, v[c]);                    // raw S entering chunk c+1
        sw[(size_t)c * DSTATE * DMODEL] = make_float4(s * CAd, Ad, Ad16, Ad32);
    }

    if (tid < 32768) {                             // b==0: j = n
        int j = n;
        float acc = (j == 0) ? Dp[h] : 0.0f;       // D folded into K[0]
        for (int m = 0; m < DSTATE; ++m) {
            float dAm = delta * A_cont(m);
            float Bd = expm1f(dAm) * B_re[m] * delta;
            acc = fmaf(C_re[m] * Bd, expf(dAm * (float)j), acc);
        }
        Kbuf[j * DMODEL + h] = acc;
    }
}

// ---------------- Kernel 3: output, 16 t' per thread, 16x16 block conv ----------------
__global__ __launch_bounds__(256) void k_out(const float* __restrict__ u,
                                             const float* __restrict__ Kbuf,
                                             const float4* __restrict__ SwT,
                                             float* __restrict__ out) {
    int tid = blockIdx.x * 256 + threadIdx.x;      // 131072 threads
    int h   = tid & (DMODEL - 1);
    int it4 = (tid >> 9) & 3;                      // t'-tile of 16 (block-uniform)
    int c   = (tid >> 11) & (NCHUNK - 1);
    int b   = tid >> 16;
    int tp0 = it4 * RT;

    const float* ub = u + ((size_t)(b * SEQLEN + c * T_CHUNK)) * DMODEL + h;
    const float* kb = Kbuf + h;

    float acc[RT];
    #pragma unroll
    for (int i = 0; i < RT; ++i) acc[i] = 0.0f;

    // full 16x16 source blocks: 47 loads -> 256 FMA each (compile-time indices)
    for (int sb = 0; sb < it4; ++sb) {
        float ureg[16], krow[31];
        int base = tp0 - sb * 16 - 15;             // >= 1
        #pragma unroll
        for (int q = 0; q < 16; ++q) ureg[q] = ub[(size_t)(sb * 16 + q) * DMODEL];
        #pragma unroll
        for (int j = 0; j < 31; ++j) krow[j] = kb[(size_t)(base + j) * DMODEL];
        #pragma unroll
        for (int q = 0; q < 16; ++q)
            #pragma unroll
            for (int i = 0; i < RT; ++i)
                acc[i] = fmaf(krow[i - q + 15], ureg[q], acc[i]);   // K[tp0+i-(sb*16+q)]
    }
    // diagonal (causal) block: 32 loads -> 136 FMA
    {
        float ureg[16], krow[16];
        #pragma unroll
        for (int q = 0; q < 16; ++q) ureg[q] = ub[(size_t)(tp0 + q) * DMODEL];
        #pragma unroll
        for (int j = 0; j < 16; ++j) krow[j] = kb[(size_t)j * DMODEL];
        #pragma unroll
        for (int q = 0; q < 16; ++q)
            #pragma unroll
            for (int i = 0; i < RT; ++i)
                if (i >= q) acc[i] = fmaf(krow[i - q], ureg[q], acc[i]);
    }
    // chunk-entry-state: acc[i] += sum_n Sw * Ad^(tp0+i);  Ad^tp0 = Ad16^it4
    if (c > 0) {
        const float4* sp = SwT + ((size_t)((b * (NCHUNK - 1) + (c - 1)) * DSTATE)) * DMODEL + h;
        bool m1 = (it4 & 1) != 0;
        bool m2 = (it4 & 2) != 0;
        #pragma unroll 4
        for (int n = 0; n < DSTATE; ++n) {
            float4 vv = sp[(size_t)n * DMODEL];    // {Sw, Ad, Ad16, Ad32}
            float w = vv.x * (m1 ? vv.z : 1.0f) * (m2 ? vv.w : 1.0f);
            acc[0] += w;
            #pragma unroll
            for (int i = 1; i < RT; ++i) { w *= vv.y; acc[i] += w; }
        }
    }
    float* ob = out + ((size_t)(b * SEQLEN + c * T_CHUNK + tp0)) * DMODEL + h;
    #pragma unroll
    for (int i = 0; i < RT; ++i) ob[(size_t)i * DMODEL] = acc[i];
}

extern "C" void kernel_launch(void* const* d_in, const int* in_sizes, int n_in,
                              void* d_out, int out_size, void* d_ws, size_t ws_size,
                              hipStream_t stream) {
    const float* u      = (const float*)d_in[0];
    const float* B_re   = (const float*)d_in[1];
    const float* C_re   = (const float*)d_in[2];
    const float* log_dt = (const float*)d_in[3];
    const float* D      = (const float*)d_in[4];
    float* out = (float*)d_out;
    float* ws  = (float*)d_ws;

    // ws layout (floats):
    float*  Kbuf = ws;                             // 64*512 = 32768 (128KB -> SwT 16B-aligned)
    float4* SwT  = (float4*)(ws + 32768);          // 2*31*64*512 float4 = 8126464 floats
    float*  xl   = ws + 32768 + 8126464;           // 2*32*64*512 = 2097152 floats

    k_xlocal <<<512, 256, 0, stream>>>(u, B_re, log_dt, xl);
    k_scanset<<<256, 256, 0, stream>>>(B_re, C_re, log_dt, D, xl, SwT, Kbuf);
    k_out    <<<512, 256, 0, stream>>>(u, Kbuf, SwT, out);
}

// Round 7
// 107.991 us; speedup vs baseline: 1.0788x; 1.0788x over previous
//
#include <hip/hip_runtime.h>
#include <math.h>

// S4 diagonal SSM: B=2, L=2048, H=512, N=64. Chunked: T=64, NC=32.
//   y[cT+t'] = sum_{tau<=t'} K[h,tau]*u[t-tau] + sum_n C[n]*Ad^(t'+1)*S_c[b,n,h]
//   K[h,tau] = sum_n C[n]*Bd[h,n]*Ad[h,n]^tau  (D folded into K[0])
//   S_c via per-chunk local end-states + fully-unrolled chunk scan.
// Lessons baked in: (R4) cooperative grid.sync ~70us/sync -- never fuse that way;
// (R6) packing state tables fat costs HBM/L2 bytes and loses ~8us -- keep the
// 8MB scalar S-table + small L1-resident Ad/Cp tables (this is the R5 structure).

#define BATCH   2
#define SEQLEN  2048
#define DMODEL  512
#define DSTATE  64
#define T_CHUNK 64
#define NCHUNK  32
#define RT      16

__device__ __forceinline__ float A_cont(int n) {
    // A[n] = (1 + (n+1)/64)^(-1/2)
    return rsqrtf(1.0f + (float)(n + 1) * (1.0f / 64.0f));
}

// ---------------- Kernel 1: xlocal[b][c][n][h] (16 states/thread) ----------------
__global__ __launch_bounds__(256) void k_xlocal(const float* __restrict__ u,
                                                const float* __restrict__ B_re,
                                                const float* __restrict__ log_dt,
                                                float* __restrict__ xl) {
    int tid = blockIdx.x * 256 + threadIdx.x;      // 131072 threads
    int h  = tid & (DMODEL - 1);
    int ng = (tid >> 9) & 3;                       // 16 n per group
    int c  = (tid >> 11) & (NCHUNK - 1);
    int b  = tid >> 16;
    float delta = expf(log_dt[h]);
    float Ad[16], Bd[16], x[16];
    #pragma unroll
    for (int nn = 0; nn < 16; ++nn) {
        int n = ng * 16 + nn;
        float dA = delta * A_cont(n);
        Ad[nn] = expf(dA);
        Bd[nn] = expm1f(dA) * B_re[n] * delta;
        x[nn] = 0.0f;
    }
    const float* up = u + ((size_t)(b * SEQLEN + c * T_CHUNK)) * DMODEL + h;
    #pragma unroll 4
    for (int s = 0; s < T_CHUNK; ++s) {
        float uv = up[(size_t)s * DMODEL];         // coalesced in h
        #pragma unroll
        for (int nn = 0; nn < 16; ++nn)
            x[nn] = fmaf(Ad[nn], x[nn], Bd[nn] * uv);
    }
    float* xp = xl + ((size_t)((b * NCHUNK + c) * DSTATE + ng * 16)) * DMODEL + h;
    #pragma unroll
    for (int nn = 0; nn < 16; ++nn) xp[(size_t)nn * DMODEL] = x[nn];
}

// ---------------- Kernel 2: chunk scan (unrolled) + table setup ----------------
// Scan: after this, xl[b][c-1][n][h] holds S_c (state entering chunk c).
// Setup (tid<32768): Kbuf[64][512] (D folded at tau=0), AdTab[64][512],
//                    CpStep[4][64][512] = C*Ad^(16i+1).
__global__ __launch_bounds__(256) void k_scanset(const float* __restrict__ B_re,
                                                 const float* __restrict__ C_re,
                                                 const float* __restrict__ log_dt,
                                                 const float* __restrict__ Dp,
                                                 float* __restrict__ xl,
                                                 float* __restrict__ Kbuf,
                                                 float* __restrict__ AdTab,
                                                 float* __restrict__ CpStep) {
    int tid = blockIdx.x * 256 + threadIdx.x;      // 65536 threads
    {
        int h = tid & (DMODEL - 1);
        int n = (tid >> 9) & (DSTATE - 1);
        int b = tid >> 15;
        float delta = expf(log_dt[h]);
        float ApT = expf(delta * A_cont(n) * (float)T_CHUNK);  // Ad^T
        float* base = xl + ((size_t)(b * NCHUNK * DSTATE + n)) * DMODEL + h;
        float v[NCHUNK - 1];
        #pragma unroll
        for (int c = 0; c < NCHUNK - 1; ++c)
            v[c] = base[(size_t)c * DSTATE * DMODEL];          // 31 independent loads
        float s = 0.0f;
        #pragma unroll
        for (int c = 0; c < NCHUNK - 1; ++c) { s = fmaf(ApT, s, v[c]); v[c] = s; }
        #pragma unroll
        for (int c = 0; c < NCHUNK - 1; ++c)
            base[(size_t)c * DSTATE * DMODEL] = v[c];
    }
    if (tid < 32768) {
        int h = tid & (DMODEL - 1);
        int j = tid >> 9;                          // 0..63
        float delta = expf(log_dt[h]);
        float Adj = expf(delta * A_cont(j));
        AdTab[j * DMODEL + h] = Adj;
        float sq = Adj * Adj; sq = sq * sq; sq = sq * sq;
        float e16 = sq * sq;                       // Adj^16
        float p = C_re[j] * Adj;                   // C*Ad^1
        #pragma unroll
        for (int i = 0; i < 4; ++i) {
            CpStep[(i * DSTATE + j) * DMODEL + h] = p;
            p *= e16;
        }
        float acc = (j == 0) ? Dp[h] : 0.0f;       // D folded into K[0]
        for (int n = 0; n < DSTATE; ++n) {
            float dAn = delta * A_cont(n);
            float Bd = expm1f(dAn) * B_re[n] * delta;
            acc = fmaf(C_re[n] * Bd, expf(dAn * (float)j), acc);
        }
        Kbuf[j * DMODEL + h] = acc;
    }
}

// ---------------- Kernel 3: output, 16 t' per thread, 16x16 block conv ----------------
__global__ __launch_bounds__(256) void k_out(const float* __restrict__ u,
                                             const float* __restrict__ Kbuf,
                                             const float* __restrict__ AdTab,
                                             const float* __restrict__ CpStep,
                                             const float* __restrict__ Sbuf,
                                             float* __restrict__ out) {
    int tid = blockIdx.x * 256 + threadIdx.x;      // 131072 threads
    int h   = tid & (DMODEL - 1);
    int it4 = (tid >> 9) & 3;                      // t'-tile of 16 (block-uniform)
    int c   = (tid >> 11) & (NCHUNK - 1);
    int b   = tid >> 16;
    int tp0 = it4 * RT;

    const float* ub = u + ((size_t)(b * SEQLEN + c * T_CHUNK)) * DMODEL + h;
    const float* kb = Kbuf + h;

    float acc[RT];
    #pragma unroll
    for (int i = 0; i < RT; ++i) acc[i] = 0.0f;

    // full 16x16 source blocks: 47 loads -> 256 FMA each (compile-time indices)
    for (int sb = 0; sb < it4; ++sb) {
        float ureg[16], krow[31];
        int base = tp0 - sb * 16 - 15;             // >= 1
        #pragma unroll
        for (int q = 0; q < 16; ++q) ureg[q] = ub[(size_t)(sb * 16 + q) * DMODEL];
        #pragma unroll
        for (int j = 0; j < 31; ++j) krow[j] = kb[(size_t)(base + j) * DMODEL];
        #pragma unroll
        for (int q = 0; q < 16; ++q)
            #pragma unroll
            for (int i = 0; i < RT; ++i)
                acc[i] = fmaf(krow[i - q + 15], ureg[q], acc[i]);   // K[tp0+i-(sb*16+q)]
    }
    // diagonal (causal) block: 32 loads -> 136 FMA
    {
        float ureg[16], krow[16];
        #pragma unroll
        for (int q = 0; q < 16; ++q) ureg[q] = ub[(size_t)(tp0 + q) * DMODEL];
        #pragma unroll
        for (int j = 0; j < 16; ++j) krow[j] = kb[(size_t)j * DMODEL];
        #pragma unroll
        for (int q = 0; q < 16; ++q)
            #pragma unroll
            for (int i = 0; i < RT; ++i)
                if (i >= q) acc[i] = fmaf(krow[i - q], ureg[q], acc[i]);
    }
    // chunk-entry-state correction: acc[i] += sum_n C*Ad^(tp0+i+1) * S[n]
    if (c > 0) {
        const float* sp = Sbuf + ((size_t)((b * NCHUNK + (c - 1)) * DSTATE)) * DMODEL + h;
        const float* ap = AdTab + h;
        const float* cp = CpStep + (size_t)(it4 * DSTATE) * DMODEL + h;
        #pragma unroll 4
        for (int n = 0; n < DSTATE; ++n) {
            float Sv  = sp[(size_t)n * DMODEL];
            float Adv = ap[(size_t)n * DMODEL];
            float w   = cp[(size_t)n * DMODEL] * Sv;
            acc[0] += w;
            #pragma unroll
            for (int i = 1; i < RT; ++i) { w *= Adv; acc[i] += w; }
        }
    }
    float* ob = out + ((size_t)(b * SEQLEN + c * T_CHUNK + tp0)) * DMODEL + h;
    #pragma unroll
    for (int i = 0; i < RT; ++i)
        __builtin_nontemporal_store(acc[i], &ob[(size_t)i * DMODEL]);  // out never re-read in-window
}

extern "C" void kernel_launch(void* const* d_in, const int* in_sizes, int n_in,
                              void* d_out, int out_size, void* d_ws, size_t ws_size,
                              hipStream_t stream) {
    const float* u      = (const float*)d_in[0];
    const float* B_re   = (const float*)d_in[1];
    const float* C_re   = (const float*)d_in[2];
    const float* log_dt = (const float*)d_in[3];
    const float* D      = (const float*)d_in[4];
    float* out = (float*)d_out;
    float* ws  = (float*)d_ws;

    // ws layout (floats):
    float* Kbuf   = ws;                            // 64*512   = 32768
    float* AdTab  = ws + 32768;                    // 64*512   = 32768
    float* CpStep = ws + 65536;                    // 4*64*512 = 131072
    float* xl     = ws + 65536 + 131072;           // 2*32*64*512 = 2097152

    k_xlocal <<<512, 256, 0, stream>>>(u, B_re, log_dt, xl);
    k_scanset<<<256, 256, 0, stream>>>(B_re, C_re, log_dt, D, xl, Kbuf, AdTab, CpStep);
    k_out    <<<512, 256, 0, stream>>>(u, Kbuf, AdTab, CpStep, xl, out);
}